// Round 12
// baseline (123.684 us; speedup 1.0000x reference)
//
#include <hip/hip_runtime.h>
#include <cmath>

typedef short s16x8 __attribute__((ext_vector_type(8)));
typedef float f32x4 __attribute__((ext_vector_type(4)));
typedef unsigned short u16;

#define MFMA(a, b, c) __builtin_amdgcn_mfma_f32_16x16x32_bf16((a), (b), (c), 0, 0, 0)

__device__ inline u16 f2b(float f) {
    union { float f; unsigned u; } v; v.f = f;
    unsigned r = v.u + 0x7fffu + ((v.u >> 16) & 1u);
    return (u16)(r >> 16);
}

// async global->LDS, 16B per lane. LDS dest: wave-uniform base + lane*16.
__device__ inline void glds16(const u16* g, u16* l) {
    __builtin_amdgcn_global_load_lds(
        (const __attribute__((address_space(1))) unsigned int*)g,
        (__attribute__((address_space(3))) unsigned int*)l, 16, 0, 0);
}

// ============================ prep: fp32 -> bf16 (+ transposes/permutes) =====
__global__ __launch_bounds__(256) void prep_kernel(
    const float* __restrict__ x,
    const float* __restrict__ qp, const float* __restrict__ kp, const float* __restrict__ vp,
    const float* __restrict__ w_out, const float* __restrict__ w1, const float* __restrict__ w2,
    u16* __restrict__ xb, u16* __restrict__ Bqkv, u16* __restrict__ w_outp,
    u16* __restrict__ w1b, u16* __restrict__ w2b)
{
    const int NXV = 262144;             // 2097152 / 8 (vectorized x)
    const int NQKV = 786432;
    const int NWO = 262144;
    const int NW1 = 524288;
    const int NW2 = 524288;
    const int TOT = NXV + NQKV + NWO + NW1 + NW2;
    for (int i = blockIdx.x * 256 + threadIdx.x; i < TOT; i += gridDim.x * 256) {
        int j = i;
        if (j < NXV) {
            const int base = j * 8;
            float4 a0 = *(const float4*)(x + base);
            float4 a1 = *(const float4*)(x + base + 4);
            s16x8 o;
            o[0]=f2b(a0.x); o[1]=f2b(a0.y); o[2]=f2b(a0.z); o[3]=f2b(a0.w);
            o[4]=f2b(a1.x); o[5]=f2b(a1.y); o[6]=f2b(a1.z); o[7]=f2b(a1.w);
            *(s16x8*)(xb + base) = o;
            continue;
        }
        j -= NXV;
        if (j < NQKV) {
            const int k = j & 63, d = (j >> 6) & 511, zh = j >> 15;
            const int z = zh >> 3, h = zh & 7;
            const float* W = (z == 0) ? qp : (z == 1) ? kp : vp;
            const float v = W[h * 32768 + d * 64 + k];
            Bqkv[(z * 512 + h * 64 + k) * 512 + d] = f2b(v);
            continue;
        }
        j -= NQKV;
        if (j < NWO) {
            const int oc = j & 511, row = j >> 9;
            const int h = oc >> 6, k = oc & 63;
            w_outp[j] = f2b(w_out[row * 512 + k * 8 + h]);
            continue;
        }
        j -= NWO;
        if (j < NW1) { w1b[j] = f2b(w1[j]); continue; }
        j -= NW1;
        w2b[j] = f2b(w2[j]);
    }
}

// ============================ MFMA GEMM core (TM x 128, BK=64) ===============
// global_load_lds w/ XOR chunk-swizzle: LDS slot (row,c) holds global chunk
// (row, c^(row&7)); ds_read applies same XOR (same involution both sides).
template<int TM>
__device__ inline void gemm_core(const u16* __restrict__ A, const u16* __restrict__ B,
                                 int K, int ktiles, int kstart, int r0, int c0,
                                 u16* As, u16* Bs, f32x4 (&acc)[TM / 32][4])
{
    const int t = threadIdx.x, lane = t & 63, wid = t >> 6;
    const int l15 = lane & 15, lg = lane >> 4, sw = l15 & 7;
    constexpr int FR = TM / 32;
    const int wr = (wid & 1) * (TM / 2), wc = (wid >> 1) * 64;
    constexpr int NA = TM * 8 / 256;    // A-stage issues per thread

    const f32x4 zero = {0.f, 0.f, 0.f, 0.f};
    #pragma unroll
    for (int fr = 0; fr < FR; ++fr)
        #pragma unroll
        for (int fc = 0; fc < 4; ++fc) acc[fr][fc] = zero;

    for (int kt = 0; kt < ktiles; ++kt) {
        const int k0 = kstart + kt * 64;
        __syncthreads();
        #pragma unroll
        for (int i = 0; i < NA; ++i) {
            const int slot = i * 256 + t;
            const int row = slot >> 3, c = slot & 7;
            glds16(A + (size_t)(r0 + row) * K + k0 + ((c ^ (row & 7)) << 3),
                   As + i * 2048 + wid * 512);
        }
        #pragma unroll
        for (int i = 0; i < 4; ++i) {
            const int slot = i * 256 + t;
            const int row = slot >> 3, c = slot & 7;
            glds16(B + (size_t)(c0 + row) * K + k0 + ((c ^ (row & 7)) << 3),
                   Bs + i * 2048 + wid * 512);
        }
        __syncthreads();
        #pragma unroll
        for (int ks = 0; ks < 2; ++ks) {
            const int cc = ((ks * 4 + lg) ^ sw) * 8;
            s16x8 af[FR], bf[4];
            #pragma unroll
            for (int f = 0; f < FR; ++f)
                af[f] = *(const s16x8*)(As + (wr + f * 16 + l15) * 64 + cc);
            #pragma unroll
            for (int f = 0; f < 4; ++f)
                bf[f] = *(const s16x8*)(Bs + (wc + f * 16 + l15) * 64 + cc);
            #pragma unroll
            for (int fr = 0; fr < FR; ++fr)
                #pragma unroll
                for (int fc = 0; fc < 4; ++fc)
                    acc[fr][fc] = MFMA(af[fr], bf[fc], acc[fr][fc]);
        }
    }
}

// ============================ QKV GEMM (TM=64): Q prescaled, V transposed ====
#define SCALE_Q 0.18033688f   /* 0.125 * log2(e): logits in log2 units */
__global__ __launch_bounds__(256) void gemm_qkv_kernel(
    const u16* __restrict__ xb, const u16* __restrict__ Bqkv,
    const float* __restrict__ qb, const float* __restrict__ kb, const float* __restrict__ vb,
    u16* __restrict__ Qb, u16* __restrict__ Kb, u16* __restrict__ Vtb)
{
    __shared__ __align__(16) u16 As[64 * 64];
    __shared__ __align__(16) u16 Bs[128 * 64];
    f32x4 acc[2][4];
    const int r0 = blockIdx.x * 64, c0 = blockIdx.y * 128;
    gemm_core<64>(xb, Bqkv, 512, 8, 0, r0, c0, As, Bs, acc);

    const int t = threadIdx.x, lane = t & 63, wid = t >> 6;
    const int wr = (wid & 1) * 32, wc = (wid >> 1) * 64;
    const int l15 = lane & 15, lg = lane >> 4;

    #pragma unroll
    for (int fc = 0; fc < 4; ++fc) {
        const int gc = c0 + wc + fc * 16 + l15;
        const int z = gc >> 9;
        const int hk = gc & 511;
        const int h = hk >> 6, k = gc & 63;
        const float bias = (z == 0 ? qb : z == 1 ? kb : vb)[hk];
        #pragma unroll
        for (int fr = 0; fr < 2; ++fr) {
            #pragma unroll
            for (int r = 0; r < 4; ++r) {
                const int grow = r0 + wr + fr * 16 + lg * 4 + r;
                const int b = grow >> 10, n = grow & 1023;
                const int bh = b * 8 + h;
                float v = acc[fr][fc][r] + bias;
                if (z == 0) v *= SCALE_Q;
                const u16 val = f2b(v);
                if (z == 0)      Qb[(size_t)bh * 65536 + n * 64 + k] = val;
                else if (z == 1) Kb[(size_t)bh * 65536 + n * 64 + k] = val;
                else             Vtb[(size_t)bh * 65536 + k * 1024 + n] = val;
            }
        }
    }
}

// ============================ generic GEMM (TM=64, optional split-K) =========
template<int EPI>   // 0: f32 out (partial via blockIdx.z), 2: bf16+bias+gelu
__global__ __launch_bounds__(256) void gemm_kernel(
    const u16* __restrict__ A, const u16* __restrict__ B, const float* __restrict__ bias,
    float* __restrict__ Cf, u16* __restrict__ Cb, int N, int K, int ktiles, size_t pstride)
{
    __shared__ __align__(16) u16 As[64 * 64];
    __shared__ __align__(16) u16 Bs[128 * 64];
    f32x4 acc[2][4];
    const int r0 = blockIdx.x * 64, c0 = blockIdx.y * 128;
    const int kstart = blockIdx.z * ktiles * 64;
    gemm_core<64>(A, B, K, ktiles, kstart, r0, c0, As, Bs, acc);
    float* Cfz = Cf + (size_t)blockIdx.z * pstride;

    const int t = threadIdx.x, lane = t & 63, wid = t >> 6;
    const int wr = (wid & 1) * 32, wc = (wid >> 1) * 64;
    const int l15 = lane & 15, lg = lane >> 4;

    #pragma unroll
    for (int fc = 0; fc < 4; ++fc) {
        const int gc = c0 + wc + fc * 16 + l15;
        const float bv = (EPI == 2) ? bias[gc] : 0.f;
        #pragma unroll
        for (int fr = 0; fr < 2; ++fr) {
            #pragma unroll
            for (int r = 0; r < 4; ++r) {
                const int grow = r0 + wr + fr * 16 + lg * 4 + r;
                float v = acc[fr][fc][r] + bv;
                if (EPI == 2) {
                    const float u = 0.7978845608028654f * (v + 0.044715f * v * v * v);
                    v = 0.5f * v * (1.0f + tanhf(u));
                    Cb[(size_t)grow * N + gc] = f2b(v);
                } else {
                    Cfz[(size_t)grow * N + gc] = v;
                }
            }
        }
    }
}

// ============================ flash attention (8-wave, single-buffer, split x4)
// r11 loop body exactly; KV-split x4 -> 1024 blocks -> 3 resident blocks/CU
// (24 waves/CU) to fill barrier/stage bubbles with other blocks' compute.
// Coords staged in LDS (global m-coords in-loop corrupts results -- verified
// r6/r8/r9; do not reintroduce). LDS = 37.4 KB. __launch_bounds__(512,4)
// (proven no-spill, VGPR ~80). Fixed-max softmax in log2 domain:
// pv = exp2(S + d2*g2 - 8). Writes unnormalized f32 O + l; 4-way merge follows.
struct AttnParams { float g2[8], lo[8], hi[8]; };

__global__ __launch_bounds__(512, 4) void attn_kernel(
    const u16* __restrict__ Qb, const u16* __restrict__ Kb, const u16* __restrict__ Vtb,
    const float* __restrict__ coords, float* __restrict__ Po, float* __restrict__ Lo,
    AttnParams prm)
{
    __shared__ __align__(16) u16 Ks[64 * 64];      // [m][k] chunk-swizzled
    __shared__ __align__(16) u16 Vs[64 * 64];      // [k][m] chunk-swizzled
    __shared__ __align__(16) u16 Ps[8][16][72];    // wave-private P rows
    __shared__ float cmx[256], cmy[256], cmz[256];

    // XCD-bijective swizzle: 1024 blocks -> each XCD owns 4 heads' K/V.
    const int wg = blockIdx.x;
    const int swz = (wg & 7) * 128 + (wg >> 3);    // 0..1023 bijective
    const int bh = swz >> 5;                       // 0..31
    const int rest = swz & 31;
    const int n0 = (rest >> 2) * 128;              // q-tile of 128 rows (8 tiles)
    const int z = rest & 3;                        // key quarter (256 keys)
    const int b = bh >> 3, h = bh & 7;
    const float g2 = prm.g2[h], lo = prm.lo[h], hi = prm.hi[h];

    const int t = threadIdx.x, lane = t & 63, wid = t >> 6;   // wid 0..7
    const int l15 = lane & 15, lg = lane >> 4, sw = l15 & 7;
    const int wq0 = wid * 16;

    const u16* Kz = Kb + (size_t)bh * 65536 + (size_t)z * 16384;   // z-quarter rows m
    const u16* Vz = Vtb + (size_t)bh * 65536 + z * 256;            // z-quarter cols m

    // stage m-quarter coords (first 256 threads, one each)
    if (t < 256) {
        const float* c = coords + ((size_t)b * 1024 + z * 256 + t) * 3;
        cmx[t] = c[0]; cmy[t] = c[1]; cmz[t] = c[2];
    }

    // Q fragments + q coords (direct from global, once)
    s16x8 qf[2];
    {
        const u16* qp_ = Qb + (size_t)bh * 65536 + (size_t)(n0 + wq0 + l15) * 64;
        qf[0] = *(const s16x8*)(qp_ + lg * 8);
        qf[1] = *(const s16x8*)(qp_ + 32 + lg * 8);
    }
    float qx[4], qy[4], qz_[4];
    #pragma unroll
    for (int r = 0; r < 4; ++r) {
        const float* c = coords + ((size_t)b * 1024 + n0 + wq0 + lg * 4 + r) * 3;
        qx[r] = c[0]; qy[r] = c[1]; qz_[r] = c[2];
    }

    f32x4 o_acc[4];
    const f32x4 zero = {0.f, 0.f, 0.f, 0.f};
    float l_lane[4] = {0.f, 0.f, 0.f, 0.f};
    #pragma unroll
    for (int kf = 0; kf < 4; ++kf) o_acc[kf] = zero;

    for (int mt = 0; mt < 4; ++mt) {
        // stage tile mt (one K slot + one V slot per thread)
        {
            const int row = t >> 3, c = t & 7;
            const int cc = (c ^ (row & 7)) << 3;
            glds16(Kz + (size_t)(mt * 64 + row) * 64 + cc, Ks + wid * 512);
            glds16(Vz + (size_t)row * 1024 + mt * 64 + cc, Vs + wid * 512);
        }
        __syncthreads();   // drains vmcnt: tile staged (and coords on mt==0)

        // m-coords from LDS
        float mx[4], my[4], mz[4];
        #pragma unroll
        for (int mf = 0; mf < 4; ++mf) {
            const int mloc = mt * 64 + mf * 16 + l15;
            mx[mf] = cmx[mloc]; my[mf] = cmy[mloc]; mz[mf] = cmz[mloc];
        }

        // S = Q K^T from LDS (swizzled reads)
        f32x4 s[4];
        #pragma unroll
        for (int mf = 0; mf < 4; ++mf) {
            const int row = mf * 16 + l15;
            s16x8 kf0 = *(const s16x8*)(Ks + row * 64 + ((lg ^ sw) << 3));
            s16x8 kf1 = *(const s16x8*)(Ks + row * 64 + (((4 + lg) ^ sw) << 3));
            f32x4 a = zero;
            a = MFMA(qf[0], kf0, a);
            a = MFMA(qf[1], kf1, a);
            s[mf] = a;
        }

        // V fragments issued early to cover Ps write->read latency
        s16x8 vfr[2][4];
        #pragma unroll
        for (int ms = 0; ms < 2; ++ms)
            #pragma unroll
            for (int kf = 0; kf < 4; ++kf) {
                const int row = kf * 16 + l15;
                vfr[ms][kf] = *(const s16x8*)(Vs + row * 64
                                              + (((ms * 4 + lg) ^ sw) << 3));
            }

        // band mask + fixed-max exp2 (no cross-lane ops in-loop)
        #pragma unroll
        for (int mf = 0; mf < 4; ++mf) {
            #pragma unroll
            for (int r = 0; r < 4; ++r) {
                const float dx = qx[r] - mx[mf], dy = qy[r] - my[mf], dz = qz_[r] - mz[mf];
                const float d2 = fmaf(dx, dx, fmaf(dy, dy, dz * dz));
                const bool valid = (d2 >= lo) && (d2 <= hi);
                float pv = exp2f(fmaf(d2, g2, s[mf][r]) - 8.0f);
                pv = valid ? pv : 0.f;
                l_lane[r] += pv;
                Ps[wid][lg * 4 + r][mf * 16 + l15] = f2b(pv);
            }
        }

        // O += P V (wave-private P; same-wave dependency only)
        #pragma unroll
        for (int ms = 0; ms < 2; ++ms) {
            s16x8 pa = *(const s16x8*)&Ps[wid][l15][ms * 32 + lg * 8];
            #pragma unroll
            for (int kf = 0; kf < 4; ++kf)
                o_acc[kf] = MFMA(pa, vfr[ms][kf], o_acc[kf]);
        }

        __syncthreads();   // all waves done reading Ks/Vs before next stage
    }

    // one l-reduce across the 16 row-lanes, after the loop
    #pragma unroll
    for (int r = 0; r < 4; ++r) {
        float v = l_lane[r];
        v += __shfl_xor(v, 1); v += __shfl_xor(v, 2);
        v += __shfl_xor(v, 4); v += __shfl_xor(v, 8);
        l_lane[r] = v;
    }

    // write unnormalized partial O (f32) + l
    float* PoZ = Po + (size_t)(z * 32 + bh) * 65536;
    #pragma unroll
    for (int kf = 0; kf < 4; ++kf)
        #pragma unroll
        for (int r = 0; r < 4; ++r) {
            const int n = n0 + wq0 + lg * 4 + r;
            PoZ[(size_t)n * 64 + kf * 16 + l15] = o_acc[kf][r];
        }
    if (l15 == 0) {
        #pragma unroll
        for (int r = 0; r < 4; ++r)
            Lo[z * 32768 + bh * 1024 + n0 + wq0 + lg * 4 + r] = l_lane[r];
    }
}

// ============================ attention merge: O=(sum Oz)/(sum lz) -> bf16 ===
__global__ __launch_bounds__(256) void attn_merge_kernel(
    const float* __restrict__ Po, const float* __restrict__ Lo, u16* __restrict__ Ob)
{
    const int gid = blockIdx.x * 256 + threadIdx.x;   // 262144 total
    const int row = gid >> 3;                          // bh*1024+n
    const int k0 = (gid & 7) * 8;
    const int bh = row >> 10, n = row & 1023;
    const int b = bh >> 3, h = bh & 7;
    float lt = 0.f;
    #pragma unroll
    for (int zz = 0; zz < 4; ++zz) lt += Lo[zz * 32768 + row];
    const float invl = (lt > 0.f) ? 1.f / lt : 0.f;
    float acc[8] = {0.f, 0.f, 0.f, 0.f, 0.f, 0.f, 0.f, 0.f};
    #pragma unroll
    for (int zz = 0; zz < 4; ++zz) {
        const float* p = Po + (size_t)zz * 2097152 + (size_t)row * 64 + k0;
        float4 a0 = *(const float4*)p;
        float4 a1 = *(const float4*)(p + 4);
        acc[0] += a0.x; acc[1] += a0.y; acc[2] += a0.z; acc[3] += a0.w;
        acc[4] += a1.x; acc[5] += a1.y; acc[6] += a1.z; acc[7] += a1.w;
    }
    s16x8 o;
    #pragma unroll
    for (int i = 0; i < 8; ++i) o[i] = f2b(acc[i] * invl);
    *(s16x8*)(Ob + ((size_t)b * 1024 + n) * 512 + h * 64 + k0) = o;
}

// ============================ fused add(+partials)(+colbias) + LayerNorm =====
template<bool CB, bool WB16>
__global__ __launch_bounds__(256) void add_ln_kernel(
    const float* __restrict__ a, const float* __restrict__ b0, const float* __restrict__ b1,
    const float* __restrict__ cb, const float* __restrict__ g, const float* __restrict__ bt,
    float* __restrict__ out, u16* __restrict__ outb)
{
    const int lane = threadIdx.x & 63;
    const int row = blockIdx.x * 4 + (threadIdx.x >> 6);
    const size_t base = (size_t)row * 512 + lane * 8;

    float v[8];
    {
        float4 a0 = *(const float4*)(a + base);
        float4 a1 = *(const float4*)(a + base + 4);
        float4 p0 = *(const float4*)(b0 + base);
        float4 p1 = *(const float4*)(b0 + base + 4);
        v[0]=a0.x+p0.x; v[1]=a0.y+p0.y; v[2]=a0.z+p0.z; v[3]=a0.w+p0.w;
        v[4]=a1.x+p1.x; v[5]=a1.y+p1.y; v[6]=a1.z+p1.z; v[7]=a1.w+p1.w;
        float4 q0 = *(const float4*)(b1 + base);
        float4 q1 = *(const float4*)(b1 + base + 4);
        v[0]+=q0.x; v[1]+=q0.y; v[2]+=q0.z; v[3]+=q0.w;
        v[4]+=q1.x; v[5]+=q1.y; v[6]+=q1.z; v[7]+=q1.w;
        if (CB) {
            float4 c0 = *(const float4*)(cb + lane * 8);
            float4 c1 = *(const float4*)(cb + lane * 8 + 4);
            v[0]+=c0.x; v[1]+=c0.y; v[2]+=c0.z; v[3]+=c0.w;
            v[4]+=c1.x; v[5]+=c1.y; v[6]+=c1.z; v[7]+=c1.w;
        }
    }
    float s = 0.f;
    #pragma unroll
    for (int k = 0; k < 8; ++k) s += v[k];
    #pragma unroll
    for (int m = 1; m <= 32; m <<= 1) s += __shfl_xor(s, m);
    const float mean = s * (1.0f / 512.0f);

    float vs = 0.f;
    #pragma unroll
    for (int k = 0; k < 8; ++k) { const float d = v[k] - mean; vs += d * d; }
    #pragma unroll
    for (int m = 1; m <= 32; m <<= 1) vs += __shfl_xor(vs, m);
    const float rstd = rsqrtf(vs * (1.0f / 512.0f) + 1e-5f);

    float4 g0 = *(const float4*)(g + lane * 8);
    float4 g1 = *(const float4*)(g + lane * 8 + 4);
    float4 t0 = *(const float4*)(bt + lane * 8);
    float4 t1 = *(const float4*)(bt + lane * 8 + 4);
    float gg[8] = {g0.x,g0.y,g0.z,g0.w,g1.x,g1.y,g1.z,g1.w};
    float tb[8] = {t0.x,t0.y,t0.z,t0.w,t1.x,t1.y,t1.z,t1.w};

    float o[8];
    #pragma unroll
    for (int k = 0; k < 8; ++k) o[k] = (v[k] - mean) * rstd * gg[k] + tb[k];
    float4 w0; w0.x=o[0]; w0.y=o[1]; w0.z=o[2]; w0.w=o[3];
    float4 w1; w1.x=o[4]; w1.y=o[5]; w1.z=o[6]; w1.w=o[7];
    *(float4*)(out + base) = w0;
    *(float4*)(out + base + 4) = w1;
    if (WB16) {
        s16x8 q;
        #pragma unroll
        for (int k = 0; k < 8; ++k) q[k] = (short)f2b(o[k]);
        *(s16x8*)(outb + base) = q;
    }
}

// ============================ launch =========================================
extern "C" void kernel_launch(void* const* d_in, const int* in_sizes, int n_in,
                              void* d_out, int out_size, void* d_ws, size_t ws_size,
                              hipStream_t stream)
{
    const float* x      = (const float*)d_in[0];
    const float* coords = (const float*)d_in[1];
    const float* qp     = (const float*)d_in[2];
    const float* kp     = (const float*)d_in[3];
    const float* vp     = (const float*)d_in[4];
    const float* qbias  = (const float*)d_in[5];
    const float* kbias  = (const float*)d_in[6];
    const float* vbias  = (const float*)d_in[7];
    const float* w_out  = (const float*)d_in[8];
    const float* ln1g   = (const float*)d_in[9];
    const float* ln1b   = (const float*)d_in[10];
    const float* w1     = (const float*)d_in[11];
    const float* b1     = (const float*)d_in[12];
    const float* w2     = (const float*)d_in[13];
    const float* b2     = (const float*)d_in[14];
    const float* ln2g   = (const float*)d_in[15];
    const float* ln2b   = (const float*)d_in[16];
    float* out = (float*)d_out;

    char* W = (char*)d_ws;
    u16*  xb     = (u16*)(W + 0);                    //  4 MiB (dead after QKV GEMM)
    u16*  Bqkv   = (u16*)(W + 4194304);              //  1.5 MiB
    u16*  w_outp = (u16*)(W + 5767168);              //  0.5 MiB
    u16*  w1b    = (u16*)(W + 6291456);              //  1 MiB
    u16*  w2b    = (u16*)(W + 7340032);              //  1 MiB
    u16*  Qb     = (u16*)(W + 8388608);              //  4 MiB
    u16*  Kb     = (u16*)(W + 12582912);             //  4 MiB
    u16*  Vtb    = (u16*)(W + 16777216);             //  4 MiB
    u16*  Ob     = (u16*)(W + 20971520);             //  4 MiB
    float* X1    = (float*)(W + 25165824);           //  8 MiB (written after merge)
    u16*  Hb     = (u16*)(W + 33554432);             //  8 MiB (written after LN1)
    float* P0    = (float*)(W + 41943040);           // 16 MiB (split-K partials)
    float* P1    = P0 + 2097152;
    u16*  X1b    = Qb;                               // reuse (Q dead after attn)
    // attn scratch (all dead before their regions are rewritten):
    float* Po    = (float*)(W + 25165824);           // 32 MiB = X1+Hb+P0 regions
    float* Lo    = (float*)(W + 0);                  // 512 KiB in xb region

    AttnParams prm;
    for (int h = 0; h < 8; ++h) {
        const double sg = 1.0 + 5.0 * (pow(20.0, (double)h / 7.0) - 1.0) / 19.0;
        const double s2 = sg * sg;
        prm.g2[h] = (float)(-1.4426950408889634 / s2);
        prm.lo[h] = (float)(2.0 * s2 * log(100.0 / 99.0));
        prm.hi[h] = (float)(2.0 * s2 * log(100.0));
    }

    prep_kernel<<<1024, 256, 0, stream>>>(x, qp, kp, vp, w_out, w1, w2,
                                          xb, Bqkv, w_outp, w1b, w2b);
    gemm_qkv_kernel<<<dim3(64, 12), 256, 0, stream>>>(xb, Bqkv, qbias, kbias, vbias,
                                                      Qb, Kb, Vtb);
    attn_kernel<<<1024, 512, 0, stream>>>(Qb, Kb, Vtb, coords, Po, Lo, prm);
    attn_merge_kernel<<<1024, 256, 0, stream>>>(Po, Lo, Ob);
    // out-proj: split-K x2 partials -> P0/P1 (Po dead after merge)
    gemm_kernel<0><<<dim3(64, 4, 2), 256, 0, stream>>>(Ob, w_outp, nullptr, P0, nullptr,
                                                       512, 512, 4, 2097152);
    add_ln_kernel<false, true><<<1024, 256, 0, stream>>>(x, P0, P1, nullptr,
                                                         ln1g, ln1b, X1, X1b);
    gemm_kernel<2><<<dim3(64, 8), 256, 0, stream>>>(X1b, w1b, b1, nullptr, Hb,
                                                    1024, 512, 8, 0);
    // ffn2: split-K x2 partials (b2 folded into LN2)
    gemm_kernel<0><<<dim3(64, 4, 2), 256, 0, stream>>>(Hb, w2b, nullptr, P0, nullptr,
                                                       512, 1024, 8, 2097152);
    add_ln_kernel<true, false><<<1024, 256, 0, stream>>>(X1, P0, P1, b2,
                                                         ln2g, ln2b, out, nullptr);
}

// Round 13
// 118.883 us; speedup vs baseline: 1.0404x; 1.0404x over previous
//
#include <hip/hip_runtime.h>
#include <cmath>

typedef short s16x8 __attribute__((ext_vector_type(8)));
typedef float f32x4 __attribute__((ext_vector_type(4)));
typedef unsigned short u16;

#define MFMA(a, b, c) __builtin_amdgcn_mfma_f32_16x16x32_bf16((a), (b), (c), 0, 0, 0)

__device__ inline u16 f2b(float f) {
    union { float f; unsigned u; } v; v.f = f;
    unsigned r = v.u + 0x7fffu + ((v.u >> 16) & 1u);
    return (u16)(r >> 16);
}

// async global->LDS, 16B per lane. LDS dest: wave-uniform base + lane*16.
__device__ inline void glds16(const u16* g, u16* l) {
    __builtin_amdgcn_global_load_lds(
        (const __attribute__((address_space(1))) unsigned int*)g,
        (__attribute__((address_space(3))) unsigned int*)l, 16, 0, 0);
}

// ============================ prep: fp32 -> bf16 (+ transposes/permutes) =====
// Bqkv transpose is output-major: one thread per (c row, 8-d chunk) -> strided
// 4B reads (L2-reused 16x across k) + coalesced 16B writes. (Old input-major
// form did 2B writes at 1KB stride: ~32x write amplification.)
__global__ __launch_bounds__(256) void prep_kernel(
    const float* __restrict__ x,
    const float* __restrict__ qp, const float* __restrict__ kp, const float* __restrict__ vp,
    const float* __restrict__ w_out, const float* __restrict__ w1, const float* __restrict__ w2,
    u16* __restrict__ xb, u16* __restrict__ Bqkv, u16* __restrict__ w_outp,
    u16* __restrict__ w1b, u16* __restrict__ w2b)
{
    const int NXV = 262144;             // 2097152 / 8 (vectorized x)
    const int NQKV8 = 98304;            // 1536 c-rows x 64 d8-chunks
    const int NWO = 262144;
    const int NW1 = 524288;
    const int NW2 = 524288;
    const int TOT = NXV + NQKV8 + NWO + NW1 + NW2;
    for (int i = blockIdx.x * 256 + threadIdx.x; i < TOT; i += gridDim.x * 256) {
        int j = i;
        if (j < NXV) {
            const int base = j * 8;
            float4 a0 = *(const float4*)(x + base);
            float4 a1 = *(const float4*)(x + base + 4);
            s16x8 o;
            o[0]=f2b(a0.x); o[1]=f2b(a0.y); o[2]=f2b(a0.z); o[3]=f2b(a0.w);
            o[4]=f2b(a1.x); o[5]=f2b(a1.y); o[6]=f2b(a1.z); o[7]=f2b(a1.w);
            *(s16x8*)(xb + base) = o;
            continue;
        }
        j -= NXV;
        if (j < NQKV8) {
            const int c = j >> 6;            // z*512 + h*64 + k, 0..1535
            const int d8 = (j & 63) * 8;
            const int z = c >> 9, hk = c & 511;
            const int h = hk >> 6, k = c & 63;
            const float* W_ = ((z == 0) ? qp : (z == 1) ? kp : vp) + h * 32768 + k;
            s16x8 o;
            #pragma unroll
            for (int q = 0; q < 8; ++q)
                o[q] = (short)f2b(W_[(d8 + q) * 64]);
            *(s16x8*)(Bqkv + (size_t)c * 512 + d8) = o;
            continue;
        }
        j -= NQKV8;
        if (j < NWO) {
            const int oc = j & 511, row = j >> 9;
            const int h = oc >> 6, k = oc & 63;
            w_outp[j] = f2b(w_out[row * 512 + k * 8 + h]);
            continue;
        }
        j -= NWO;
        if (j < NW1) { w1b[j] = f2b(w1[j]); continue; }
        j -= NW1;
        w2b[j] = f2b(w2[j]);
    }
}

// ============================ MFMA GEMM core (TM x 128, BK=64) ===============
// global_load_lds w/ XOR chunk-swizzle: LDS slot (row,c) holds global chunk
// (row, c^(row&7)); ds_read applies same XOR (same involution both sides).
template<int TM>
__device__ inline void gemm_core(const u16* __restrict__ A, const u16* __restrict__ B,
                                 int K, int ktiles, int kstart, int r0, int c0,
                                 u16* As, u16* Bs, f32x4 (&acc)[TM / 32][4])
{
    const int t = threadIdx.x, lane = t & 63, wid = t >> 6;
    const int l15 = lane & 15, lg = lane >> 4, sw = l15 & 7;
    constexpr int FR = TM / 32;
    const int wr = (wid & 1) * (TM / 2), wc = (wid >> 1) * 64;
    constexpr int NA = TM * 8 / 256;    // A-stage issues per thread

    const f32x4 zero = {0.f, 0.f, 0.f, 0.f};
    #pragma unroll
    for (int fr = 0; fr < FR; ++fr)
        #pragma unroll
        for (int fc = 0; fc < 4; ++fc) acc[fr][fc] = zero;

    for (int kt = 0; kt < ktiles; ++kt) {
        const int k0 = kstart + kt * 64;
        __syncthreads();
        #pragma unroll
        for (int i = 0; i < NA; ++i) {
            const int slot = i * 256 + t;
            const int row = slot >> 3, c = slot & 7;
            glds16(A + (size_t)(r0 + row) * K + k0 + ((c ^ (row & 7)) << 3),
                   As + i * 2048 + wid * 512);
        }
        #pragma unroll
        for (int i = 0; i < 4; ++i) {
            const int slot = i * 256 + t;
            const int row = slot >> 3, c = slot & 7;
            glds16(B + (size_t)(c0 + row) * K + k0 + ((c ^ (row & 7)) << 3),
                   Bs + i * 2048 + wid * 512);
        }
        __syncthreads();
        #pragma unroll
        for (int ks = 0; ks < 2; ++ks) {
            const int cc = ((ks * 4 + lg) ^ sw) * 8;
            s16x8 af[FR], bf[4];
            #pragma unroll
            for (int f = 0; f < FR; ++f)
                af[f] = *(const s16x8*)(As + (wr + f * 16 + l15) * 64 + cc);
            #pragma unroll
            for (int f = 0; f < 4; ++f)
                bf[f] = *(const s16x8*)(Bs + (wc + f * 16 + l15) * 64 + cc);
            #pragma unroll
            for (int fr = 0; fr < FR; ++fr)
                #pragma unroll
                for (int fc = 0; fc < 4; ++fc)
                    acc[fr][fc] = MFMA(af[fr], bf[fc], acc[fr][fc]);
        }
    }
}

// ============================ QKV GEMM (TM=64): Q prescaled, V transposed ====
#define SCALE_Q 0.18033688f   /* 0.125 * log2(e): logits in log2 units */
__global__ __launch_bounds__(256) void gemm_qkv_kernel(
    const u16* __restrict__ xb, const u16* __restrict__ Bqkv,
    const float* __restrict__ qb, const float* __restrict__ kb, const float* __restrict__ vb,
    u16* __restrict__ Qb, u16* __restrict__ Kb, u16* __restrict__ Vtb)
{
    __shared__ __align__(16) u16 As[64 * 64];
    __shared__ __align__(16) u16 Bs[128 * 64];
    f32x4 acc[2][4];
    const int r0 = blockIdx.x * 64, c0 = blockIdx.y * 128;
    gemm_core<64>(xb, Bqkv, 512, 8, 0, r0, c0, As, Bs, acc);

    const int t = threadIdx.x, lane = t & 63, wid = t >> 6;
    const int wr = (wid & 1) * 32, wc = (wid >> 1) * 64;
    const int l15 = lane & 15, lg = lane >> 4;

    #pragma unroll
    for (int fc = 0; fc < 4; ++fc) {
        const int gc = c0 + wc + fc * 16 + l15;
        const int z = gc >> 9;
        const int hk = gc & 511;
        const int h = hk >> 6, k = gc & 63;
        const float bias = (z == 0 ? qb : z == 1 ? kb : vb)[hk];
        #pragma unroll
        for (int fr = 0; fr < 2; ++fr) {
            #pragma unroll
            for (int r = 0; r < 4; ++r) {
                const int grow = r0 + wr + fr * 16 + lg * 4 + r;
                const int b = grow >> 10, n = grow & 1023;
                const int bh = b * 8 + h;
                float v = acc[fr][fc][r] + bias;
                if (z == 0) v *= SCALE_Q;
                const u16 val = f2b(v);
                if (z == 0)      Qb[(size_t)bh * 65536 + n * 64 + k] = val;
                else if (z == 1) Kb[(size_t)bh * 65536 + n * 64 + k] = val;
                else             Vtb[(size_t)bh * 65536 + k * 1024 + n] = val;
            }
        }
    }
}

// ============================ generic GEMM (TM=64, optional split-K) =========
template<int EPI>   // 0: f32 out (partial via blockIdx.z), 2: bf16+bias+gelu
__global__ __launch_bounds__(256) void gemm_kernel(
    const u16* __restrict__ A, const u16* __restrict__ B, const float* __restrict__ bias,
    float* __restrict__ Cf, u16* __restrict__ Cb, int N, int K, int ktiles, size_t pstride)
{
    __shared__ __align__(16) u16 As[64 * 64];
    __shared__ __align__(16) u16 Bs[128 * 64];
    f32x4 acc[2][4];
    const int r0 = blockIdx.x * 64, c0 = blockIdx.y * 128;
    const int kstart = blockIdx.z * ktiles * 64;
    gemm_core<64>(A, B, K, ktiles, kstart, r0, c0, As, Bs, acc);
    float* Cfz = Cf + (size_t)blockIdx.z * pstride;

    const int t = threadIdx.x, lane = t & 63, wid = t >> 6;
    const int wr = (wid & 1) * 32, wc = (wid >> 1) * 64;
    const int l15 = lane & 15, lg = lane >> 4;

    #pragma unroll
    for (int fc = 0; fc < 4; ++fc) {
        const int gc = c0 + wc + fc * 16 + l15;
        const float bv = (EPI == 2) ? bias[gc] : 0.f;
        #pragma unroll
        for (int fr = 0; fr < 2; ++fr) {
            #pragma unroll
            for (int r = 0; r < 4; ++r) {
                const int grow = r0 + wr + fr * 16 + lg * 4 + r;
                float v = acc[fr][fc][r] + bv;
                if (EPI == 2) {
                    const float u = 0.7978845608028654f * (v + 0.044715f * v * v * v);
                    v = 0.5f * v * (1.0f + tanhf(u));
                    Cb[(size_t)grow * N + gc] = f2b(v);
                } else {
                    Cfz[(size_t)grow * N + gc] = v;
                }
            }
        }
    }
}

// ============================ flash attention (8-wave, LDS-staged, fixed-max) =
// r7-proven structure (best measured: 119.0 us total). 512 threads = 8 waves,
// 128 q-rows per block; staged 64-key K/V tiles shared by all waves. 2-phase
// double-buffered pipeline, one barrier per tile. Fixed-max softmax in log2
// domain (Q prescaled): pv = exp2(S + d2*g2 - 8). Coords staged in LDS
// (global m-coords in-loop corrupts results -- verified r6/r8/r9; do not
// reintroduce). KV-split x2; writes unnormalized f32 O + l; merge follows.
struct AttnParams { float g2[8], lo[8], hi[8]; };

__global__ __launch_bounds__(512, 4) void attn_kernel(
    const u16* __restrict__ Qb, const u16* __restrict__ Kb, const u16* __restrict__ Vtb,
    const float* __restrict__ coords, float* __restrict__ Po, float* __restrict__ Lo,
    AttnParams prm)
{
    __shared__ __align__(16) u16 Ks[2][64 * 64];   // [buf][m][k] chunk-swizzled
    __shared__ __align__(16) u16 Vs[2][64 * 64];   // [buf][k][m] chunk-swizzled
    __shared__ __align__(16) u16 Ps[8][16][72];    // wave-private P rows
    __shared__ float cmx[512], cmy[512], cmz[512];

    // XCD-bijective swizzle: 512 blocks -> each XCD owns 4 heads' K/V.
    const int wg = blockIdx.x;
    const int swz = (wg & 7) * 64 + (wg >> 3);     // 0..511 bijective
    const int bh = swz >> 4;                       // 0..31
    const int rest = swz & 15;
    const int n0 = (rest >> 1) * 128;              // q-tile of 128 rows
    const int z = rest & 1;                        // key half
    const int b = bh >> 3, h = bh & 7;
    const float g2 = prm.g2[h], lo = prm.lo[h], hi = prm.hi[h];

    const int t = threadIdx.x, lane = t & 63, wid = t >> 6;   // wid 0..7
    const int l15 = lane & 15, lg = lane >> 4, sw = l15 & 7;
    const int wq0 = wid * 16;

    const u16* Kz = Kb + (size_t)bh * 65536 + (size_t)z * 32768;   // z-half rows m
    const u16* Vz = Vtb + (size_t)bh * 65536 + z * 512;            // z-half cols m

    // stage m-half coords (512 threads, one each)
    {
        const float* c = coords + ((size_t)b * 1024 + z * 512 + t) * 3;
        cmx[t] = c[0]; cmy[t] = c[1]; cmz[t] = c[2];
    }

    // Q fragments + q coords (direct from global, once)
    s16x8 qf[2];
    {
        const u16* qp_ = Qb + (size_t)bh * 65536 + (size_t)(n0 + wq0 + l15) * 64;
        qf[0] = *(const s16x8*)(qp_ + lg * 8);
        qf[1] = *(const s16x8*)(qp_ + 32 + lg * 8);
    }
    float qx[4], qy[4], qz_[4];
    #pragma unroll
    for (int r = 0; r < 4; ++r) {
        const float* c = coords + ((size_t)b * 1024 + n0 + wq0 + lg * 4 + r) * 3;
        qx[r] = c[0]; qy[r] = c[1]; qz_[r] = c[2];
    }

    // prologue: stage tile 0 into buf 0 (one K slot + one V slot per thread)
    {
        const int row = t >> 3, c = t & 7;
        const int cc = (c ^ (row & 7)) << 3;
        glds16(Kz + (size_t)row * 64 + cc, &Ks[0][0] + wid * 512);
        glds16(Vz + (size_t)row * 1024 + cc, &Vs[0][0] + wid * 512);
    }
    __syncthreads();   // coords + tile0 staged

    f32x4 o_acc[4];
    const f32x4 zero = {0.f, 0.f, 0.f, 0.f};
    float l_lane[4] = {0.f, 0.f, 0.f, 0.f};
    #pragma unroll
    for (int kf = 0; kf < 4; ++kf) o_acc[kf] = zero;

    for (int mt = 0; mt < 8; ++mt) {
        const int cur = mt & 1;

        // stage tile mt+1 into the other buffer (overlaps with compute below)
        if (mt < 7) {
            const int mnext = (mt + 1) * 64;
            const int row = t >> 3, c = t & 7;
            const int cc = (c ^ (row & 7)) << 3;
            glds16(Kz + (size_t)(mnext + row) * 64 + cc, &Ks[cur ^ 1][0] + wid * 512);
            glds16(Vz + (size_t)row * 1024 + mnext + cc, &Vs[cur ^ 1][0] + wid * 512);
        }

        // m-coords from LDS
        float mx[4], my[4], mz[4];
        #pragma unroll
        for (int mf = 0; mf < 4; ++mf) {
            const int mloc = mt * 64 + mf * 16 + l15;
            mx[mf] = cmx[mloc]; my[mf] = cmy[mloc]; mz[mf] = cmz[mloc];
        }

        // S = Q K^T from LDS (swizzled reads)
        f32x4 s[4];
        #pragma unroll
        for (int mf = 0; mf < 4; ++mf) {
            const int row = mf * 16 + l15;
            s16x8 kf0 = *(const s16x8*)(&Ks[cur][0] + row * 64 + ((lg ^ sw) << 3));
            s16x8 kf1 = *(const s16x8*)(&Ks[cur][0] + row * 64 + (((4 + lg) ^ sw) << 3));
            f32x4 a = zero;
            a = MFMA(qf[0], kf0, a);
            a = MFMA(qf[1], kf1, a);
            s[mf] = a;
        }

        // V fragments issued early to cover Ps write->read latency
        s16x8 vfr[2][4];
        #pragma unroll
        for (int ms = 0; ms < 2; ++ms)
            #pragma unroll
            for (int kf = 0; kf < 4; ++kf) {
                const int row = kf * 16 + l15;
                vfr[ms][kf] = *(const s16x8*)(&Vs[cur][0] + row * 64
                                              + (((ms * 4 + lg) ^ sw) << 3));
            }

        // band mask + fixed-max exp2 (no cross-lane ops in-loop)
        #pragma unroll
        for (int mf = 0; mf < 4; ++mf) {
            #pragma unroll
            for (int r = 0; r < 4; ++r) {
                const float dx = qx[r] - mx[mf], dy = qy[r] - my[mf], dz = qz_[r] - mz[mf];
                const float d2 = fmaf(dx, dx, fmaf(dy, dy, dz * dz));
                const bool valid = (d2 >= lo) && (d2 <= hi);
                float pv = exp2f(fmaf(d2, g2, s[mf][r]) - 8.0f);
                pv = valid ? pv : 0.f;
                l_lane[r] += pv;
                Ps[wid][lg * 4 + r][mf * 16 + l15] = f2b(pv);
            }
        }

        // O += P V (wave-private P; same-wave dependency only)
        #pragma unroll
        for (int ms = 0; ms < 2; ++ms) {
            s16x8 pa = *(const s16x8*)&Ps[wid][l15][ms * 32 + lg * 8];
            #pragma unroll
            for (int kf = 0; kf < 4; ++kf)
                o_acc[kf] = MFMA(pa, vfr[ms][kf], o_acc[kf]);
        }

        __syncthreads();   // drain stage(mt+1); all waves done with buf[cur]
    }

    // one l-reduce across the 16 row-lanes, after the loop
    #pragma unroll
    for (int r = 0; r < 4; ++r) {
        float v = l_lane[r];
        v += __shfl_xor(v, 1); v += __shfl_xor(v, 2);
        v += __shfl_xor(v, 4); v += __shfl_xor(v, 8);
        l_lane[r] = v;
    }

    // write unnormalized partial O (f32) + l
    float* PoZ = Po + (size_t)(z * 32 + bh) * 65536;
    #pragma unroll
    for (int kf = 0; kf < 4; ++kf)
        #pragma unroll
        for (int r = 0; r < 4; ++r) {
            const int n = n0 + wq0 + lg * 4 + r;
            PoZ[(size_t)n * 64 + kf * 16 + l15] = o_acc[kf][r];
        }
    if (l15 == 0) {
        #pragma unroll
        for (int r = 0; r < 4; ++r)
            Lo[z * 32768 + bh * 1024 + n0 + wq0 + lg * 4 + r] = l_lane[r];
    }
}

// ============================ attention merge: O=(O0+O1)/(l0+l1) -> bf16 =====
__global__ __launch_bounds__(256) void attn_merge_kernel(
    const float* __restrict__ Po, const float* __restrict__ Lo, u16* __restrict__ Ob)
{
    const int gid = blockIdx.x * 256 + threadIdx.x;   // 262144 total
    const int row = gid >> 3;                          // bh*1024+n
    const int k0 = (gid & 7) * 8;
    const int bh = row >> 10, n = row & 1023;
    const int b = bh >> 3, h = bh & 7;
    const float l0 = Lo[row], l1 = Lo[32768 + row];
    const float lt = l0 + l1;
    const float invl = (lt > 0.f) ? 1.f / lt : 0.f;
    const float* p0 = Po + (size_t)row * 64 + k0;
    const float* p1 = Po + 2097152 + (size_t)row * 64 + k0;
    float4 a0 = *(const float4*)p0;
    float4 a1 = *(const float4*)(p0 + 4);
    float4 b0 = *(const float4*)p1;
    float4 b1 = *(const float4*)(p1 + 4);
    s16x8 o;
    o[0] = f2b((a0.x + b0.x) * invl);
    o[1] = f2b((a0.y + b0.y) * invl);
    o[2] = f2b((a0.z + b0.z) * invl);
    o[3] = f2b((a0.w + b0.w) * invl);
    o[4] = f2b((a1.x + b1.x) * invl);
    o[5] = f2b((a1.y + b1.y) * invl);
    o[6] = f2b((a1.z + b1.z) * invl);
    o[7] = f2b((a1.w + b1.w) * invl);
    *(s16x8*)(Ob + ((size_t)b * 1024 + n) * 512 + h * 64 + k0) = o;
}

// ============================ fused add(+partials)(+colbias) + LayerNorm =====
template<bool CB, bool WB16>
__global__ __launch_bounds__(256) void add_ln_kernel(
    const float* __restrict__ a, const float* __restrict__ b0, const float* __restrict__ b1,
    const float* __restrict__ cb, const float* __restrict__ g, const float* __restrict__ bt,
    float* __restrict__ out, u16* __restrict__ outb)
{
    const int lane = threadIdx.x & 63;
    const int row = blockIdx.x * 4 + (threadIdx.x >> 6);
    const size_t base = (size_t)row * 512 + lane * 8;

    float v[8];
    {
        float4 a0 = *(const float4*)(a + base);
        float4 a1 = *(const float4*)(a + base + 4);
        float4 p0 = *(const float4*)(b0 + base);
        float4 p1 = *(const float4*)(b0 + base + 4);
        v[0]=a0.x+p0.x; v[1]=a0.y+p0.y; v[2]=a0.z+p0.z; v[3]=a0.w+p0.w;
        v[4]=a1.x+p1.x; v[5]=a1.y+p1.y; v[6]=a1.z+p1.z; v[7]=a1.w+p1.w;
        float4 q0 = *(const float4*)(b1 + base);
        float4 q1 = *(const float4*)(b1 + base + 4);
        v[0]+=q0.x; v[1]+=q0.y; v[2]+=q0.z; v[3]+=q0.w;
        v[4]+=q1.x; v[5]+=q1.y; v[6]+=q1.z; v[7]+=q1.w;
        if (CB) {
            float4 c0 = *(const float4*)(cb + lane * 8);
            float4 c1 = *(const float4*)(cb + lane * 8 + 4);
            v[0]+=c0.x; v[1]+=c0.y; v[2]+=c0.z; v[3]+=c0.w;
            v[4]+=c1.x; v[5]+=c1.y; v[6]+=c1.z; v[7]+=c1.w;
        }
    }
    float s = 0.f;
    #pragma unroll
    for (int k = 0; k < 8; ++k) s += v[k];
    #pragma unroll
    for (int m = 1; m <= 32; m <<= 1) s += __shfl_xor(s, m);
    const float mean = s * (1.0f / 512.0f);

    float vs = 0.f;
    #pragma unroll
    for (int k = 0; k < 8; ++k) { const float d = v[k] - mean; vs += d * d; }
    #pragma unroll
    for (int m = 1; m <= 32; m <<= 1) vs += __shfl_xor(vs, m);
    const float rstd = rsqrtf(vs * (1.0f / 512.0f) + 1e-5f);

    float4 g0 = *(const float4*)(g + lane * 8);
    float4 g1 = *(const float4*)(g + lane * 8 + 4);
    float4 t0 = *(const float4*)(bt + lane * 8);
    float4 t1 = *(const float4*)(bt + lane * 8 + 4);
    float gg[8] = {g0.x,g0.y,g0.z,g0.w,g1.x,g1.y,g1.z,g1.w};
    float tb[8] = {t0.x,t0.y,t0.z,t0.w,t1.x,t1.y,t1.z,t1.w};

    float o[8];
    #pragma unroll
    for (int k = 0; k < 8; ++k) o[k] = (v[k] - mean) * rstd * gg[k] + tb[k];
    float4 w0; w0.x=o[0]; w0.y=o[1]; w0.z=o[2]; w0.w=o[3];
    float4 w1; w1.x=o[4]; w1.y=o[5]; w1.z=o[6]; w1.w=o[7];
    *(float4*)(out + base) = w0;
    *(float4*)(out + base + 4) = w1;
    if (WB16) {
        s16x8 q;
        #pragma unroll
        for (int k = 0; k < 8; ++k) q[k] = (short)f2b(o[k]);
        *(s16x8*)(outb + base) = q;
    }
}

// ============================ launch =========================================
extern "C" void kernel_launch(void* const* d_in, const int* in_sizes, int n_in,
                              void* d_out, int out_size, void* d_ws, size_t ws_size,
                              hipStream_t stream)
{
    const float* x      = (const float*)d_in[0];
    const float* coords = (const float*)d_in[1];
    const float* qp     = (const float*)d_in[2];
    const float* kp     = (const float*)d_in[3];
    const float* vp     = (const float*)d_in[4];
    const float* qbias  = (const float*)d_in[5];
    const float* kbias  = (const float*)d_in[6];
    const float* vbias  = (const float*)d_in[7];
    const float* w_out  = (const float*)d_in[8];
    const float* ln1g   = (const float*)d_in[9];
    const float* ln1b   = (const float*)d_in[10];
    const float* w1     = (const float*)d_in[11];
    const float* b1     = (const float*)d_in[12];
    const float* w2     = (const float*)d_in[13];
    const float* b2     = (const float*)d_in[14];
    const float* ln2g   = (const float*)d_in[15];
    const float* ln2b   = (const float*)d_in[16];
    float* out = (float*)d_out;

    char* W = (char*)d_ws;
    u16*  xb     = (u16*)(W + 0);                    //  4 MiB
    u16*  Bqkv   = (u16*)(W + 4194304);              //  1.5 MiB
    u16*  w_outp = (u16*)(W + 5767168);              //  0.5 MiB
    u16*  w1b    = (u16*)(W + 6291456);              //  1 MiB
    u16*  w2b    = (u16*)(W + 7340032);              //  1 MiB
    u16*  Qb     = (u16*)(W + 8388608);              //  4 MiB
    u16*  Kb     = (u16*)(W + 12582912);             //  4 MiB
    u16*  Vtb    = (u16*)(W + 16777216);             //  4 MiB
    u16*  Ob     = (u16*)(W + 20971520);             //  4 MiB
    float* X1    = (float*)(W + 25165824);           //  8 MiB
    u16*  Hb     = (u16*)(W + 33554432);             //  8 MiB
    float* P0    = (float*)(W + 41943040);           // 16 MiB (split partials)
    float* P1    = P0 + 2097152;
    u16*  X1b    = Qb;                               // reuse (Q dead after attn)
    float* Po    = P0;                               // attn partials (dead before out-proj)
    float* Lo    = X1;                               // attn l-stats (dead before LN1)

    AttnParams prm;
    for (int h = 0; h < 8; ++h) {
        const double sg = 1.0 + 5.0 * (pow(20.0, (double)h / 7.0) - 1.0) / 19.0;
        const double s2 = sg * sg;
        prm.g2[h] = (float)(-1.4426950408889634 / s2);
        prm.lo[h] = (float)(2.0 * s2 * log(100.0 / 99.0));
        prm.hi[h] = (float)(2.0 * s2 * log(100.0));
    }

    prep_kernel<<<1024, 256, 0, stream>>>(x, qp, kp, vp, w_out, w1, w2,
                                          xb, Bqkv, w_outp, w1b, w2b);
    gemm_qkv_kernel<<<dim3(64, 12), 256, 0, stream>>>(xb, Bqkv, qbias, kbias, vbias,
                                                      Qb, Kb, Vtb);
    attn_kernel<<<512, 512, 0, stream>>>(Qb, Kb, Vtb, coords, Po, Lo, prm);
    attn_merge_kernel<<<1024, 256, 0, stream>>>(Po, Lo, Ob);
    // out-proj: split-K x2 partials -> P0/P1
    gemm_kernel<0><<<dim3(64, 4, 2), 256, 0, stream>>>(Ob, w_outp, nullptr, P0, nullptr,
                                                       512, 512, 4, 2097152);
    add_ln_kernel<false, true><<<1024, 256, 0, stream>>>(x, P0, P1, nullptr,
                                                         ln1g, ln1b, X1, X1b);
    gemm_kernel<2><<<dim3(64, 8), 256, 0, stream>>>(X1b, w1b, b1, nullptr, Hb,
                                                    1024, 512, 8, 0);
    // ffn2: split-K x2 partials (b2 folded into LN2)
    gemm_kernel<0><<<dim3(64, 4, 2), 256, 0, stream>>>(Hb, w2b, nullptr, P0, nullptr,
                                                       512, 1024, 8, 2097152);
    add_ln_kernel<true, false><<<1024, 256, 0, stream>>>(X1, P0, P1, b2,
                                                         ln2g, ln2b, out, nullptr);
}